// Round 8
// baseline (15035.333 us; speedup 1.0000x reference)
//
#include <hip/hip_runtime.h>
#include <hip/hip_bf16.h>

#define B_   256
#define T_   64
#define OBS_ 1024
#define ACT_ 6
#define STO_ 32
#define HID_ 1024

using bf16 = __bf16;
typedef __attribute__((ext_vector_type(8))) __bf16 bf16x8;
typedef __attribute__((ext_vector_type(4))) float f32x4;

__device__ __forceinline__ f32x4 MF(bf16x8 a, bf16x8 b, f32x4 c) {
  return __builtin_amdgcn_mfma_f32_16x16x32_bf16(a, b, c, 0, 0, 0);
}

// ---- fine-grained flags: per-wave spin (relaxed) + one acquire ----
__device__ __forceinline__ void waitctr(unsigned* c, unsigned tgt) {
  if ((threadIdx.x & 63) == 0) {
    while (__hip_atomic_load(c, __ATOMIC_RELAXED, __HIP_MEMORY_SCOPE_AGENT) < tgt)
      __builtin_amdgcn_s_sleep(1);
    __hip_atomic_load(c, __ATOMIC_ACQUIRE, __HIP_MEMORY_SCOPE_AGENT);
  }
  __builtin_amdgcn_wave_barrier();
  asm volatile("" ::: "memory");
}
__device__ __forceinline__ void signalctr(unsigned* c) {
  __syncthreads();   // all waves' stores drained (vmcnt0) before release
  if (threadIdx.x == 0)
    __hip_atomic_fetch_add(c, 1u, __ATOMIC_RELEASE, __HIP_MEMORY_SCOPE_AGENT);
}

// ---- 64m x 128n GEMM tile, 8 waves (4 msub x 2 nsub), K=1024, no split ----
__device__ __forceinline__ void gemm128(
    const bf16* __restrict__ A, int m0,
    const bf16* __restrict__ W,                 // pre-offset to n-tile row base
    const float* __restrict__ bias,             // pre-offset (local col) or null
    const float* __restrict__ accb, size_t accLd,  // pre-offset or null
    bf16* __restrict__ outb, int ldo) {
  const int tid = threadIdx.x, lane = tid & 63, wv = tid >> 6;
  const int l15 = lane & 15, kg = lane >> 4, kq = kg << 3, rq = kg << 2;
  const int mrow = m0 + (wv & 3) * 16;
  const int nb = (wv >> 2) * 64;
  f32x4 a0{0.f,0.f,0.f,0.f}, a1 = a0, a2 = a0, a3 = a0;
  const bf16* __restrict__ ap = A + (size_t)(mrow + l15) * 1024 + kq;
  const bf16* __restrict__ wp = W + (size_t)(nb + l15) * 1024 + kq;
  #pragma unroll 4
  for (int k = 0; k < 1024; k += 32) {
    bf16x8 af = *(const bf16x8*)(ap + k);
    a0 = MF(af, *(const bf16x8*)(wp + k            ), a0);
    a1 = MF(af, *(const bf16x8*)(wp + 16*1024 + k  ), a1);
    a2 = MF(af, *(const bf16x8*)(wp + 32*1024 + k  ), a2);
    a3 = MF(af, *(const bf16x8*)(wp + 48*1024 + k  ), a3);
  }
  f32x4 aa[4] = {a0, a1, a2, a3};
  #pragma unroll
  for (int nf = 0; nf < 4; ++nf) {
    const int col = nb + nf * 16 + l15;
    const float bv = bias ? bias[col] : 0.f;
    #pragma unroll
    for (int r = 0; r < 4; ++r) {
      const int row = mrow + rq + r;
      float v = aa[nf][r] + bv;
      if (accb) v += accb[(size_t)row * accLd + col];
      v = fmaxf(v, 0.f);
      outb[(size_t)row * ldo + col] = (bf16)v;
    }
  }
}

struct SPar {
  const bf16 *w_in2, *w_wih, *w_whh, *w_pr1, *w_po1h, *w_pr2, *w_po2, *w_head;
  const float *b_in2, *b_ih, *b_hh, *b_pr1, *b_pr2, *b_po2;
  const float *pr_mb, *pr_sb, *po_mb, *po_sb;
  const float *eps, *act, *in_w1, *in_b1;
  bf16 *x1b, *x2b, *p1b, *q1b, *p2b, *q2b, *hbA, *hbB;
  float *hfA, *hfB;
  const float *q1acc;
  float *feat, *pm, *ps, *qm, *qs;
  unsigned *ctr;
};

// counters per step (stride 32): kind*4 + mt; kinds: 0 x2(8) 1 h(16) 2 q1(8) 3 pr1(8) 4 q2(8) 5 pr2(8)
__global__ __launch_bounds__(512) void k_step(SPar P, int t) {
  __shared__ float shmem[10048];
  const int bid = blockIdx.x, tid = threadIdx.x;
  const int lane = tid & 63, wv = tid >> 6;
  const int l15 = lane & 15, kg = lane >> 4, kq = kg << 3, rq = kg << 2;
  unsigned* cc = P.ctr + t * 32;
  bf16* hbCur  = (t & 1) ? P.hbB : P.hbA;
  const bf16* hbPrev = (t & 1) ? P.hbA : P.hbB;
  float* hfCur = (t & 1) ? P.hfB : P.hfA;
  const float* hfPrev = (t & 1) ? P.hfA : P.hfB;

  if (bid < 32) {
    // ---- S1: x2 = relu(x1 @ in_w2^T + b2) ----
    const int mt = bid & 3, nt = bid >> 2;
    gemm128(P.x1b, mt * 64, P.w_in2 + (size_t)nt * 128 * 1024,
            P.b_in2 + nt * 128, nullptr, 0, P.x2b + nt * 128, 1024);
    signalctr(&cc[0 * 4 + mt]);

  } else if (bid < 96) {
    // ---- S2: gh (no wait) ; wait x2 ; gi ; GRU gates -> h ----
    const int idx = bid - 32, mt = idx & 3, cs = idx >> 2;       // cs 0..15
    const int msub = wv & 3, nsh = wv >> 2;                      // nsh 0..1
    const int mrow = mt * 64 + msub * 16;
    const int cb = cs * 64 + nsh * 32;
    f32x4 gh[3][2], gi[3][2];
    #pragma unroll
    for (int g = 0; g < 3; ++g)
      #pragma unroll
      for (int nf = 0; nf < 2; ++nf) { gh[g][nf] = f32x4{0.f,0.f,0.f,0.f}; gi[g][nf] = gh[g][nf]; }

    {
      const bf16* __restrict__ ap = hbPrev + (size_t)(mrow + l15) * 1024 + kq;
      const bf16* wr[3][2];
      #pragma unroll
      for (int g = 0; g < 3; ++g)
        #pragma unroll
        for (int nf = 0; nf < 2; ++nf)
          wr[g][nf] = P.w_whh + (size_t)(g * 1024 + cb + nf * 16 + l15) * 1024 + kq;
      #pragma unroll 2
      for (int k = 0; k < 1024; k += 32) {
        bf16x8 af = *(const bf16x8*)(ap + k);
        #pragma unroll
        for (int g = 0; g < 3; ++g)
          #pragma unroll
          for (int nf = 0; nf < 2; ++nf)
            gh[g][nf] = MF(af, *(const bf16x8*)(wr[g][nf] + k), gh[g][nf]);
      }
    }
    waitctr(&cc[0 * 4 + mt], 8);
    {
      const bf16* __restrict__ ap = P.x2b + (size_t)(mrow + l15) * 1024 + kq;
      const bf16* wr[3][2];
      #pragma unroll
      for (int g = 0; g < 3; ++g)
        #pragma unroll
        for (int nf = 0; nf < 2; ++nf)
          wr[g][nf] = P.w_wih + (size_t)(g * 1024 + cb + nf * 16 + l15) * 1024 + kq;
      #pragma unroll 2
      for (int k = 0; k < 1024; k += 32) {
        bf16x8 af = *(const bf16x8*)(ap + k);
        #pragma unroll
        for (int g = 0; g < 3; ++g)
          #pragma unroll
          for (int nf = 0; nf < 2; ++nf)
            gi[g][nf] = MF(af, *(const bf16x8*)(wr[g][nf] + k), gi[g][nf]);
      }
    }
    #pragma unroll
    for (int nf = 0; nf < 2; ++nf) {
      const int col = cb + nf * 16 + l15;
      const float bir = P.b_ih[col], biz = P.b_ih[1024 + col], bin_ = P.b_ih[2048 + col];
      const float bhr = P.b_hh[col], bhz = P.b_hh[1024 + col], bhn = P.b_hh[2048 + col];
      #pragma unroll
      for (int r = 0; r < 4; ++r) {
        const int row = mrow + rq + r;
        float rr = gi[0][nf][r] + bir + gh[0][nf][r] + bhr;
        float zz = gi[1][nf][r] + biz + gh[1][nf][r] + bhz;
        const float hn = gh[2][nf][r] + bhn;
        rr = 1.f / (1.f + __expf(-rr));
        zz = 1.f / (1.f + __expf(-zz));
        const float nn = tanhf(gi[2][nf][r] + bin_ + rr * hn);
        const float h2 = (1.f - zz) * nn + zz * hfPrev[(size_t)row * 1024 + col];
        hbCur[(size_t)row * 1024 + col] = (bf16)h2;
        hfCur[(size_t)row * 1024 + col] = h2;
        P.feat[((size_t)row * T_ + t) * 1056 + col] = h2;
      }
    }
    signalctr(&cc[1 * 4 + mt]);

  } else if (bid < 128) {
    // ---- S3a: q1 = relu(h @ W_po1h + q1acc_t) ----
    const int idx = bid - 96, mt = idx & 3, nt = idx >> 2;
    waitctr(&cc[1 * 4 + mt], 16);
    gemm128(hbCur, mt * 64, P.w_po1h + (size_t)nt * 128 * 1024, nullptr,
            P.q1acc + (size_t)t * 1024 + nt * 128, (size_t)T_ * 1024,
            P.q1b + nt * 128, 1024);
    signalctr(&cc[2 * 4 + mt]);

  } else if (bid < 160) {
    // ---- S3b: pr1 = relu(h @ pr_w1^T + b) ----
    const int idx = bid - 128, mt = idx & 3, nt = idx >> 2;
    waitctr(&cc[1 * 4 + mt], 16);
    gemm128(hbCur, mt * 64, P.w_pr1 + (size_t)nt * 128 * 1024,
            P.b_pr1 + nt * 128, nullptr, 0, P.p1b + nt * 128, 1024);
    signalctr(&cc[3 * 4 + mt]);

  } else if (bid < 192) {
    // ---- S4a: q2 ----
    const int idx = bid - 160, mt = idx & 3, nt = idx >> 2;
    waitctr(&cc[2 * 4 + mt], 8);
    gemm128(P.q1b, mt * 64, P.w_po2 + (size_t)nt * 128 * 1024,
            P.b_po2 + nt * 128, nullptr, 0, P.q2b + nt * 128, 1024);
    signalctr(&cc[4 * 4 + mt]);

  } else if (bid < 224) {
    // ---- S4b: pr2 ----
    const int idx = bid - 192, mt = idx & 3, nt = idx >> 2;
    waitctr(&cc[3 * 4 + mt], 8);
    gemm128(P.p1b, mt * 64, P.w_pr2 + (size_t)nt * 128 * 1024,
            P.b_pr2 + nt * 128, nullptr, 0, P.p2b + nt * 128, 1024);
    signalctr(&cc[5 * 4 + mt]);

  } else {
    // ---- S5: heads + stats + z + feat_z + next x1  (16 blocks, rows m0..m0+15) ----
    const int g = bid - 224, m0 = g * 16, mt = g >> 2;
    waitctr(&cc[4 * 4 + mt], 8);
    waitctr(&cc[5 * 4 + mt], 8);
    float* sh = shmem;           // 8 x 1056
    float* zm = shmem + 8448;    // 16 x 32
    float* zs = zm + 512;
    float* zl = zs + 512;
    float* al = zl + 512;        // 16 x 8
    {
      const int kw = wv & 3, half = wv >> 2;
      const bf16* __restrict__ A = half ? P.q2b : P.p2b;
      f32x4 c0{0.f,0.f,0.f,0.f}, c1 = c0, c2 = c0, c3 = c0;
      const bf16* __restrict__ ap = A + (size_t)(m0 + l15) * 1024 + kw * 256 + kq;
      const bf16* __restrict__ wp = P.w_head + (size_t)(half * 64 + l15) * 1024 + kw * 256 + kq;
      #pragma unroll
      for (int k = 0; k < 256; k += 32) {
        bf16x8 af = *(const bf16x8*)(ap + k);
        c0 = MF(af, *(const bf16x8*)(wp + k            ), c0);
        c1 = MF(af, *(const bf16x8*)(wp + 16*1024 + k  ), c1);
        c2 = MF(af, *(const bf16x8*)(wp + 32*1024 + k  ), c2);
        c3 = MF(af, *(const bf16x8*)(wp + 48*1024 + k  ), c3);
      }
      f32x4 ccx[4] = {c0, c1, c2, c3};
      float* s = sh + wv * 1056;
      #pragma unroll
      for (int t2 = 0; t2 < 4; ++t2)
        #pragma unroll
        for (int r = 0; r < 4; ++r)
          s[(rq + r) * 66 + t2 * 16 + l15] = ccx[t2][r];
    }
    if (tid < 96) {
      const int r = tid / ACT_, k = tid - r * ACT_;
      al[r * 8 + k] = P.act[((size_t)(m0 + r) * T_ + t) * ACT_ + k];
    }
    __syncthreads();
    #pragma unroll
    for (int rep = 0; rep < 4; ++rep) {
      const int idx = rep * 512 + tid;       // 16 rows x 128 cols
      const int r = idx >> 7, c = idx & 127;
      const int base = (c < 64) ? 0 : 4, cl = c & 63, j = c & 31;
      float v = sh[base * 1056 + r * 66 + cl] + sh[(base + 1) * 1056 + r * 66 + cl]
              + sh[(base + 2) * 1056 + r * 66 + cl] + sh[(base + 3) * 1056 + r * 66 + cl];
      const size_t ob = ((size_t)(m0 + r) * T_ + t) * STO_ + j;
      const int sel = c >> 5;
      if (sel == 0) {
        P.pm[ob] = v + P.pr_mb[j];
      } else if (sel == 1) {
        P.ps[ob] = __expf(fminf(fmaxf(v + P.pr_sb[j], -5.f), 2.f));
      } else if (sel == 2) {
        const float x = v + P.po_mb[j];
        P.qm[ob] = x; zm[r * 32 + j] = x;
      } else {
        const float x = __expf(fminf(fmaxf(v + P.po_sb[j], -5.f), 2.f));
        P.qs[ob] = x; zs[r * 32 + j] = x;
      }
    }
    __syncthreads();
    {
      const int r = tid >> 5, j = tid & 31;    // 512 = 16x32
      const float z = zm[r * 32 + j] + zs[r * 32 + j] * P.eps[((size_t)(m0 + r) * T_ + t) * STO_ + j];
      zl[r * 32 + j] = z;
      P.feat[((size_t)(m0 + r) * T_ + t) * 1056 + 1024 + j] = z;
    }
    __syncthreads();
    #pragma unroll
    for (int c2 = 0; c2 < 2; ++c2) {
      const int n = c2 * 512 + tid;
      const float* w = P.in_w1 + (size_t)n * 38;
      float wreg[38];
      #pragma unroll
      for (int j = 0; j < 38; ++j) wreg[j] = w[j];
      const float bn = P.in_b1[n];
      #pragma unroll 2
      for (int r = 0; r < 16; ++r) {
        float a = bn;
        #pragma unroll
        for (int k = 0; k < STO_; ++k) a = fmaf(zl[r * 32 + k], wreg[k], a);
        #pragma unroll
        for (int k = 0; k < ACT_; ++k) a = fmaf(al[r * 8 + k], wreg[32 + k], a);
        P.x1b[(size_t)(m0 + r) * 1024 + n] = (bf16)fmaxf(a, 0.f);
      }
    }
  }
}

// ---------------- prologue kernels ----------------
struct CvtArgs {
  const float *in_w2, *gru_wih, *gru_whh, *pr_w1, *pr_w2, *po_w1, *po_w2;
  const float *pr_mw, *pr_sw, *po_mw, *po_sw;
  bf16 *w_in2b, *w_wihb, *w_whhb, *w_pr1b, *w_pr2b, *w_po1hb, *w_po1ob, *w_po2b, *w_headb;
};

__global__ void k_cvtall(CvtArgs a) {
  const int row = blockIdx.x;            // 12416 rows
  const float* src; bf16* dst;
  if      (row < 1024)  { src = a.in_w2   + (size_t)row * 1024;               dst = a.w_in2b  + (size_t)row * 1024; }
  else if (row < 4096)  { int r = row - 1024;  src = a.gru_wih + (size_t)r * 1024;        dst = a.w_wihb  + (size_t)r * 1024; }
  else if (row < 7168)  { int r = row - 4096;  src = a.gru_whh + (size_t)r * 1024;        dst = a.w_whhb  + (size_t)r * 1024; }
  else if (row < 8192)  { int r = row - 7168;  src = a.pr_w1   + (size_t)r * 1024;        dst = a.w_pr1b  + (size_t)r * 1024; }
  else if (row < 9216)  { int r = row - 8192;  src = a.pr_w2   + (size_t)r * 1024;        dst = a.w_pr2b  + (size_t)r * 1024; }
  else if (row < 10240) { int r = row - 9216;  src = a.po_w1   + (size_t)r * 2048;        dst = a.w_po1hb + (size_t)r * 1024; }
  else if (row < 11264) { int r = row - 10240; src = a.po_w1   + (size_t)r * 2048 + 1024; dst = a.w_po1ob + (size_t)r * 1024; }
  else if (row < 12288) { int r = row - 11264; src = a.po_w2   + (size_t)r * 1024;        dst = a.w_po2b  + (size_t)r * 1024; }
  else {
    int r = row - 12288;
    const float* hs[4] = { a.pr_mw, a.pr_sw, a.po_mw, a.po_sw };
    src = hs[r >> 5] + (size_t)(r & 31) * 1024;
    dst = a.w_headb + (size_t)r * 1024;
  }
  const int c = threadIdx.x * 4;
  float4 f = *(const float4*)(src + c);
  dst[c] = (bf16)f.x; dst[c + 1] = (bf16)f.y; dst[c + 2] = (bf16)f.z; dst[c + 3] = (bf16)f.w;
}

__global__ void k_init(const float* __restrict__ in_b1, bf16* __restrict__ x1b,
                       bf16* __restrict__ hbA, bf16* __restrict__ hbB,
                       float* __restrict__ hfA, float* __restrict__ hfB) {
  const int i = blockIdx.x * 256 + threadIdx.x;      // < 262144
  x1b[i] = (bf16)fmaxf(in_b1[i & 1023], 0.f);        // z0=0, a0=0
  hbA[i] = (bf16)0.f; hbB[i] = (bf16)0.f;
  hfA[i] = 0.f; hfB[i] = 0.f;
}

__global__ __launch_bounds__(256) void k_qbatch(
    const float* __restrict__ obs, const bf16* __restrict__ w,
    const float* __restrict__ bias, float* __restrict__ out) {
  const int tid = threadIdx.x, lane = tid & 63, wv = tid >> 6;
  const int l15 = lane & 15, kg = lane >> 4, kq = kg * 8, rq = kg * 4;
  const int m0 = (blockIdx.x & 255) * 64 + wv * 16;
  const int n0 = (blockIdx.x >> 8) * 64;
  f32x4 c0{0.f,0.f,0.f,0.f}, c1 = c0, c2 = c0, c3 = c0;
  const float* __restrict__ ap = obs + (size_t)(m0 + l15) * 1024 + kq;
  const bf16* __restrict__ wp = w + (size_t)(n0 + l15) * 1024 + kq;
  #pragma unroll 2
  for (int k = 0; k < 1024; k += 32) {
    float4 f0 = *(const float4*)(ap + k);
    float4 f1 = *(const float4*)(ap + k + 4);
    bf16x8 af;
    af[0] = (bf16)f0.x; af[1] = (bf16)f0.y; af[2] = (bf16)f0.z; af[3] = (bf16)f0.w;
    af[4] = (bf16)f1.x; af[5] = (bf16)f1.y; af[6] = (bf16)f1.z; af[7] = (bf16)f1.w;
    c0 = MF(af, *(const bf16x8*)(wp + k            ), c0);
    c1 = MF(af, *(const bf16x8*)(wp + 16 * 1024 + k), c1);
    c2 = MF(af, *(const bf16x8*)(wp + 32 * 1024 + k), c2);
    c3 = MF(af, *(const bf16x8*)(wp + 48 * 1024 + k), c3);
  }
  f32x4 cc[4] = {c0, c1, c2, c3};
  #pragma unroll
  for (int t2 = 0; t2 < 4; ++t2) {
    const int n = n0 + t2 * 16 + l15;
    const float bv = bias[n];
    #pragma unroll
    for (int r = 0; r < 4; ++r)
      out[(size_t)(m0 + rq + r) * 1024 + n] = cc[t2][r] + bv;
  }
}

extern "C" void kernel_launch(void* const* d_in, const int* in_sizes, int n_in,
                              void* d_out, int out_size, void* d_ws, size_t ws_size,
                              hipStream_t stream) {
  (void)in_sizes; (void)n_in; (void)out_size; (void)ws_size;
  const float* obs      = (const float*)d_in[0];
  const float* actions  = (const float*)d_in[1];
  const float* eps_post = (const float*)d_in[3];   // eps_prior unused by the math
  const float* in_w1 = (const float*)d_in[4];
  const float* in_b1 = (const float*)d_in[5];
  const float* in_w2 = (const float*)d_in[6];
  const float* in_b2 = (const float*)d_in[7];
  const float* gru_wih = (const float*)d_in[8];
  const float* gru_whh = (const float*)d_in[9];
  const float* gru_bih = (const float*)d_in[10];
  const float* gru_bhh = (const float*)d_in[11];
  const float* pr_w1 = (const float*)d_in[12];
  const float* pr_b1 = (const float*)d_in[13];
  const float* pr_w2 = (const float*)d_in[14];
  const float* pr_b2 = (const float*)d_in[15];
  const float* pr_mw = (const float*)d_in[16];
  const float* pr_mb = (const float*)d_in[17];
  const float* pr_sw = (const float*)d_in[18];
  const float* pr_sb = (const float*)d_in[19];
  const float* po_w1 = (const float*)d_in[20];
  const float* po_b1 = (const float*)d_in[21];
  const float* po_w2 = (const float*)d_in[22];
  const float* po_b2 = (const float*)d_in[23];
  const float* po_mw = (const float*)d_in[24];
  const float* po_mb = (const float*)d_in[25];
  const float* po_sw = (const float*)d_in[26];
  const float* po_sb = (const float*)d_in[27];

  float* feat = (float*)d_out;
  float* pm = feat + (size_t)B_ * T_ * 1056;
  float* ps = pm + (size_t)B_ * T_ * STO_;
  float* qm = ps + (size_t)B_ * T_ * STO_;
  float* qs = qm + (size_t)B_ * T_ * STO_;

  char* wp_ = (char*)d_ws;
  auto carve = [&](size_t bytes) -> void* {
    void* r = (void*)wp_;
    wp_ += (bytes + 255) & ~(size_t)255;
    return r;
  };
  bf16* w_in2b  = (bf16*)carve((size_t)HID_ * HID_ * 2);
  bf16* w_wihb  = (bf16*)carve((size_t)3 * HID_ * HID_ * 2);
  bf16* w_whhb  = (bf16*)carve((size_t)3 * HID_ * HID_ * 2);
  bf16* w_pr1b  = (bf16*)carve((size_t)HID_ * HID_ * 2);
  bf16* w_pr2b  = (bf16*)carve((size_t)HID_ * HID_ * 2);
  bf16* w_po1hb = (bf16*)carve((size_t)HID_ * HID_ * 2);
  bf16* w_po1ob = (bf16*)carve((size_t)HID_ * OBS_ * 2);
  bf16* w_po2b  = (bf16*)carve((size_t)HID_ * HID_ * 2);
  bf16* w_headb = (bf16*)carve((size_t)128 * HID_ * 2);
  bf16* x1b = (bf16*)carve((size_t)B_ * HID_ * 2);
  bf16* x2b = (bf16*)carve((size_t)B_ * HID_ * 2);
  bf16* hbA = (bf16*)carve((size_t)B_ * HID_ * 2);
  bf16* hbB = (bf16*)carve((size_t)B_ * HID_ * 2);
  bf16* p1b = (bf16*)carve((size_t)B_ * HID_ * 2);
  bf16* q1b = (bf16*)carve((size_t)B_ * HID_ * 2);
  bf16* p2b = (bf16*)carve((size_t)B_ * HID_ * 2);
  bf16* q2b = (bf16*)carve((size_t)B_ * HID_ * 2);
  float* hfA = (float*)carve((size_t)B_ * HID_ * 4);
  float* hfB = (float*)carve((size_t)B_ * HID_ * 4);
  float* q1acc = (float*)carve((size_t)B_ * T_ * HID_ * 4);   // 64 MB
  unsigned* ctr = (unsigned*)carve((size_t)T_ * 32 * 4);

  hipMemsetAsync(ctr, 0, (size_t)T_ * 32 * 4, stream);

  CvtArgs ca = { in_w2, gru_wih, gru_whh, pr_w1, pr_w2, po_w1, po_w2,
                 pr_mw, pr_sw, po_mw, po_sw,
                 w_in2b, w_wihb, w_whhb, w_pr1b, w_pr2b, w_po1hb, w_po1ob, w_po2b, w_headb };
  k_cvtall<<<dim3(12416), dim3(256), 0, stream>>>(ca);
  k_init<<<dim3(1024), dim3(256), 0, stream>>>(in_b1, x1b, hbA, hbB, hfA, hfB);
  k_qbatch<<<dim3(4096), dim3(256), 0, stream>>>(obs, w_po1ob, po_b1, q1acc);

  SPar P;
  P.w_in2 = w_in2b; P.w_wih = w_wihb; P.w_whh = w_whhb; P.w_pr1 = w_pr1b;
  P.w_po1h = w_po1hb; P.w_pr2 = w_pr2b; P.w_po2 = w_po2b; P.w_head = w_headb;
  P.b_in2 = in_b2; P.b_ih = gru_bih; P.b_hh = gru_bhh;
  P.b_pr1 = pr_b1; P.b_pr2 = pr_b2; P.b_po2 = po_b2;
  P.pr_mb = pr_mb; P.pr_sb = pr_sb; P.po_mb = po_mb; P.po_sb = po_sb;
  P.eps = eps_post; P.act = actions; P.in_w1 = in_w1; P.in_b1 = in_b1;
  P.x1b = x1b; P.x2b = x2b; P.p1b = p1b; P.q1b = q1b; P.p2b = p2b; P.q2b = q2b;
  P.hbA = hbA; P.hbB = hbB; P.hfA = hfA; P.hfB = hfB;
  P.q1acc = q1acc;
  P.feat = feat; P.pm = pm; P.ps = ps; P.qm = qm; P.qs = qs;
  P.ctr = ctr;

  for (int t = 0; t < T_; ++t)
    k_step<<<dim3(240), dim3(512), 0, stream>>>(P, t);
}